// Round 1
// baseline (3265.007 us; speedup 1.0000x reference)
//
#include <hip/hip_runtime.h>
#include <hip/hip_bf16.h>

// ---------- types ----------
typedef __attribute__((ext_vector_type(8))) short short8;   // 8 x bf16 bits
typedef __attribute__((ext_vector_type(4))) float f32x4;

__device__ __forceinline__ ushort f2bf(float f) {
  uint32_t u = __float_as_uint(f);
  uint32_t r = (u + 0x7FFFu + ((u >> 16) & 1u)) >> 16;
  return (ushort)r;
}
__device__ __forceinline__ float bf2f(ushort u) {
  return __uint_as_float(((uint32_t)u) << 16);
}

__device__ __forceinline__ void gload_lds16(const ushort* g, ushort* l) {
  __builtin_amdgcn_global_load_lds(
      (const __attribute__((address_space(1))) void*)g,
      (__attribute__((address_space(3))) void*)l, 16, 0, 0);
}

// ---------- transpose + fp32->bf16 convert: W[K][N] -> WT[N][K] ----------
__global__ __launch_bounds__(256)
void transpose_conv_kernel(const float* __restrict__ W, ushort* __restrict__ WT,
                           const int K, const int N) {
  __shared__ float tile[32][33];
  const int n0 = blockIdx.x * 32;
  const int k0 = blockIdx.y * 32;
  const int x = threadIdx.x;   // 0..31
  const int y = threadIdx.y;   // 0..7
#pragma unroll
  for (int j = 0; j < 4; ++j)
    tile[y + j * 8][x] = W[(size_t)(k0 + y + j * 8) * N + n0 + x];
  __syncthreads();
#pragma unroll
  for (int j = 0; j < 4; ++j)
    WT[(size_t)(n0 + y + j * 8) * K + k0 + x] = f2bf(tile[x][y + j * 8]);
}

// ---------- embedding gather (table row 0 forced to zero) ----------
__global__ __launch_bounds__(256)
void embed_kernel(const int* __restrict__ tokens, const float* __restrict__ table,
                  float* __restrict__ emb) {
  const int s = blockIdx.x, t = threadIdx.x;
  const int tok = tokens[s];
  float4 v = make_float4(0.f, 0.f, 0.f, 0.f);
  if (tok != 0) v = *(const float4*)&table[(size_t)tok * 1024 + t * 4];
  *(float4*)&emb[(size_t)s * 1024 + t * 4] = v;
}

// ---------- rmsnorm over 1024 cols: f32 in -> bf16 out ----------
__global__ __launch_bounds__(256)
void rmsnorm_kernel(const float* __restrict__ x, ushort* __restrict__ out) {
  const int row = blockIdx.x, t = threadIdx.x;
  const float4 v = *(const float4*)&x[(size_t)row * 1024 + t * 4];
  float ss = v.x * v.x + v.y * v.y + v.z * v.z + v.w * v.w;
#pragma unroll
  for (int off = 32; off; off >>= 1) ss += __shfl_xor(ss, off);
  __shared__ float red[4];
  if ((t & 63) == 0) red[t >> 6] = ss;
  __syncthreads();
  const float total = red[0] + red[1] + red[2] + red[3];
  const float sc = rsqrtf(total * (1.f / 1024.f) + 1e-5f);
  ushort4 o;
  o.x = f2bf(v.x * sc); o.y = f2bf(v.y * sc);
  o.z = f2bf(v.z * sc); o.w = f2bf(v.w * sc);
  *(ushort4*)&out[(size_t)row * 1024 + t * 4] = o;
}

// ---------- RoPE + head-major split: qkv[s][3072] -> qh/kh/vh[h][s][64] f32 ----------
__global__ __launch_bounds__(256)
void rope_kernel(const float* __restrict__ qkv, float* __restrict__ qh,
                 float* __restrict__ kh, float* __restrict__ vh) {
  const int s = blockIdx.x;
  const int t = threadIdx.x;
  const int e0 = t * 4;            // element in [0,1024)
  const int hh = e0 >> 6;
  const int d0 = e0 & 63;
  const float* row = qkv + (size_t)s * 3072;
  const int part = hh * 64 + ((d0 + 32) & 63);
  const float4 xq  = *(const float4*)&row[e0];
  const float4 xqs = *(const float4*)&row[part];
  const float4 xk  = *(const float4*)&row[1024 + e0];
  const float4 xks = *(const float4*)&row[1024 + part];
  const float4 xv  = *(const float4*)&row[2048 + e0];
  float co[4], si[4];
#pragma unroll
  for (int c = 0; c < 4; ++c) {
    const int d = d0 + c;
    const int off = d & 31;
    const float freq = exp2f(-0.41524101186092029f * (float)off); // 10000^(-off/32)
    const float ang = (float)s * freq;
    co[c] = cosf(ang);
    const float sv = sinf(ang);
    si[c] = (d < 32) ? -sv : sv;
  }
  float4 oq, ok;
  oq.x = co[0] * xq.x + si[0] * xqs.x;
  oq.y = co[1] * xq.y + si[1] * xqs.y;
  oq.z = co[2] * xq.z + si[2] * xqs.z;
  oq.w = co[3] * xq.w + si[3] * xqs.w;
  ok.x = co[0] * xk.x + si[0] * xks.x;
  ok.y = co[1] * xk.y + si[1] * xks.y;
  ok.z = co[2] * xk.z + si[2] * xks.z;
  ok.w = co[3] * xk.w + si[3] * xks.w;
  const size_t ho = ((size_t)hh * 2048 + s) * 64 + d0;
  *(float4*)&qh[ho] = oq;
  *(float4*)&kh[ho] = ok;
  *(float4*)&vh[ho] = xv;
}

// ---------- flash attention, fp32, causal; block = (4 rows, 1 head), 4 waves ----------
__global__ __launch_bounds__(256)
void attn_kernel(const float* __restrict__ qh, const float* __restrict__ kh,
                 const float* __restrict__ vh, ushort* __restrict__ attn_out) {
  __shared__ float kbuf[64][68];   // padded: row stride 272B breaks bank aliasing
  __shared__ float vbuf[64][68];
  __shared__ float qbuf[4][64];
  const int h = blockIdx.y;
  const int i0 = blockIdx.x * 4;
  const int tid = threadIdx.x;
  const int w = tid >> 6;
  const int lane = tid & 63;
  const int i = i0 + w;
  const int llo = lane & 15, g = lane >> 4;
  qbuf[w][lane] = qh[((size_t)h * 2048 + i) * 64 + lane];
  float m = -1e30f, lsum = 0.f;
  float ox = 0.f, oy = 0.f, oz = 0.f, ow = 0.f;
  const int nch = i0 / 64 + 1;
  for (int cb = 0; cb < nch; ++cb) {
    const int kb = cb * 64;
    __syncthreads();
#pragma unroll
    for (int chk = 0; chk < 4; ++chk) {
      const int e = (tid + chk * 256) * 4;
      const int r = e >> 6, c = e & 63;
      *(float4*)&kbuf[r][c] = *(const float4*)&kh[((size_t)h * 2048 + kb + r) * 64 + c];
      *(float4*)&vbuf[r][c] = *(const float4*)&vh[((size_t)h * 2048 + kb + r) * 64 + c];
    }
    __syncthreads();
    float s = -1e30f;
    if (kb + lane <= i) {
      float acc = 0.f;
#pragma unroll
      for (int d4 = 0; d4 < 16; ++d4) {
        const float4 k4 = *(const float4*)&kbuf[lane][d4 * 4];
        const float4 q4 = *(const float4*)&qbuf[w][d4 * 4];
        acc += q4.x * k4.x + q4.y * k4.y + q4.z * k4.z + q4.w * k4.w;
      }
      s = acc * 0.125f;
    }
    float mt = s;
#pragma unroll
    for (int off = 32; off; off >>= 1) mt = fmaxf(mt, __shfl_xor(mt, off));
    const float mnew = fmaxf(m, mt);
    const float p = __expf(s - mnew);     // masked lanes underflow to 0
    float psum = p;
#pragma unroll
    for (int off = 32; off; off >>= 1) psum += __shfl_xor(psum, off);
    const float scale = __expf(m - mnew);
    lsum = lsum * scale + psum;
    m = mnew;
    ox *= scale; oy *= scale; oz *= scale; ow *= scale;
#pragma unroll
    for (int jj = 0; jj < 16; ++jj) {
      const float pj = __shfl(p, g * 16 + jj);   // P lives in this lane-group
      const float4 v4 = *(const float4*)&vbuf[g * 16 + jj][llo * 4];
      ox += pj * v4.x; oy += pj * v4.y; oz += pj * v4.z; ow += pj * v4.w;
    }
  }
#pragma unroll
  for (int off = 16; off <= 32; off <<= 1) {
    ox += __shfl_xor(ox, off);
    oy += __shfl_xor(oy, off);
    oz += __shfl_xor(oz, off);
    ow += __shfl_xor(ow, off);
  }
  if (g == 0) {
    const float inv = 1.f / lsum;
    ushort4 o;
    o.x = f2bf(ox * inv); o.y = f2bf(oy * inv);
    o.z = f2bf(oz * inv); o.w = f2bf(ow * inv);
    *(ushort4*)&attn_out[(size_t)i * 1024 + h * 64 + llo * 4] = o;
  }
}

// ---------- SiLU(gate) * up : gateup[2048][8192] bf16 -> h[2048][4096] bf16 ----------
__global__ __launch_bounds__(256)
void silu_mul_kernel(const ushort* __restrict__ gu, ushort* __restrict__ hb) {
  const int idx = blockIdx.x * 256 + threadIdx.x;
  const int i = idx * 4;
  const int r = i >> 12;
  const int c = i & 4095;
  const ushort4 g4 = *(const ushort4*)&gu[(size_t)r * 8192 + c];
  const ushort4 u4 = *(const ushort4*)&gu[(size_t)r * 8192 + 4096 + c];
  ushort4 o;
  {
    float gv = bf2f(g4.x), uv = bf2f(u4.x);
    o.x = f2bf(uv * gv / (1.f + expf(-gv)));
  }
  {
    float gv = bf2f(g4.y), uv = bf2f(u4.y);
    o.y = f2bf(uv * gv / (1.f + expf(-gv)));
  }
  {
    float gv = bf2f(g4.z), uv = bf2f(u4.z);
    o.z = f2bf(uv * gv / (1.f + expf(-gv)));
  }
  {
    float gv = bf2f(g4.w), uv = bf2f(u4.w);
    o.w = f2bf(uv * gv / (1.f + expf(-gv)));
  }
  *(ushort4*)&hb[(size_t)r * 4096 + c] = o;
}

// ---------- bf16 MFMA GEMM: C[M][N] = A[M][K] * BT[N][K]^T (+ addend) ----------
// EPI: 0 = f32 store, 1 = f32 addend + store, 2 = bf16 store
template <int BM, int BN, int EPI>
__global__ __launch_bounds__(256)
void gemm_bt_kernel(const ushort* __restrict__ A, const ushort* __restrict__ BT,
                    const float* __restrict__ addend, void* __restrict__ Cout,
                    const int M, const int N, const int K) {
  constexpr int WM = BM / 2, WN = BN / 2;
  constexpr int FM = WM / 16, FN = WN / 16;
  constexpr int CHA = BM / 16, CHB = BN / 16;   // 1KB staging chunks
  __shared__ ushort sA[BM * 32];
  __shared__ ushort sB[BN * 32];
  const int bm0 = blockIdx.y * BM;
  const int bn0 = blockIdx.x * BN;
  const int tid = threadIdx.x;
  const int wid = tid >> 6;
  const int lane = tid & 63;
  const int wr = wid >> 1, wc = wid & 1;
  const int lhi = lane >> 4, llo = lane & 15;
  f32x4 acc[FM][FN] = {};
  for (int kt = 0; kt < K; kt += 32) {
#pragma unroll
    for (int c2 = 0; c2 < CHA / 4; ++c2) {
      const int ch = c2 * 4 + wid;
      const int e = ch * 512 + lane * 8;
      gload_lds16(A + (size_t)(bm0 + (e >> 5)) * K + kt + (e & 31), sA + ch * 512);
    }
#pragma unroll
    for (int c2 = 0; c2 < CHB / 4; ++c2) {
      const int ch = c2 * 4 + wid;
      const int e = ch * 512 + lane * 8;
      gload_lds16(BT + (size_t)(bn0 + (e >> 5)) * K + kt + (e & 31), sB + ch * 512);
    }
    __syncthreads();
    short8 aF[FM], bF[FN];
#pragma unroll
    for (int mm = 0; mm < FM; ++mm)
      aF[mm] = *(const short8*)&sA[(wr * WM + mm * 16 + llo) * 32 + lhi * 8];
#pragma unroll
    for (int nn = 0; nn < FN; ++nn)
      bF[nn] = *(const short8*)&sB[(wc * WN + nn * 16 + llo) * 32 + lhi * 8];
#pragma unroll
    for (int mm = 0; mm < FM; ++mm)
#pragma unroll
      for (int nn = 0; nn < FN; ++nn)
        acc[mm][nn] = __builtin_amdgcn_mfma_f32_16x16x32_bf16(aF[mm], bF[nn],
                                                              acc[mm][nn], 0, 0, 0);
    __syncthreads();
  }
  // epilogue: C/D layout col = lane&15, row = (lane>>4)*4 + reg
#pragma unroll
  for (int mm = 0; mm < FM; ++mm) {
#pragma unroll
    for (int nn = 0; nn < FN; ++nn) {
      const int col = bn0 + wc * WN + nn * 16 + llo;
#pragma unroll
      for (int r = 0; r < 4; ++r) {
        const int row = bm0 + wr * WM + mm * 16 + lhi * 4 + r;
        float v = acc[mm][nn][r];
        if constexpr (EPI == 2) {
          ((ushort*)Cout)[(size_t)row * N + col] = f2bf(v);
        } else {
          if constexpr (EPI == 1) v += addend[(size_t)row * N + col];
          ((float*)Cout)[(size_t)row * N + col] = v;
        }
      }
    }
  }
}

// ---------- launch ----------
extern "C" void kernel_launch(void* const* d_in, const int* in_sizes, int n_in,
                              void* d_out, int out_size, void* d_ws, size_t ws_size,
                              hipStream_t stream) {
  const int* tokens    = (const int*)d_in[0];
  const float* table   = (const float*)d_in[1];
  const float* qkv_w   = (const float*)d_in[2];
  const float* out_w   = (const float*)d_in[3];
  const float* up_w    = (const float*)d_in[4];
  const float* down_w  = (const float*)d_in[5];
  const float* vocab_w = (const float*)d_in[6];
  float* logits = (float*)d_out;

  char* p = (char*)d_ws;
  auto alloc = [&](size_t bytes) {
    char* r = p;
    p += (bytes + 255) & ~(size_t)255;
    return r;
  };
  float*  emb    = (float*)alloc(2048ull * 1024 * 4);
  ushort* normed = (ushort*)alloc(2048ull * 1024 * 2);
  float*  qkvbuf = (float*)alloc(2048ull * 3072 * 4);
  float*  qhf    = (float*)alloc(2048ull * 1024 * 4);
  float*  khf    = (float*)alloc(2048ull * 1024 * 4);
  float*  vhf    = (float*)alloc(2048ull * 1024 * 4);
  ushort* attno  = (ushort*)alloc(2048ull * 1024 * 2);
  ushort* gateup = (ushort*)alloc(2048ull * 8192 * 2);
  ushort* hbuf   = (ushort*)alloc(2048ull * 4096 * 2);
  ushort* qkvT   = (ushort*)alloc(4ull * 3072 * 1024 * 2);
  ushort* outT   = (ushort*)alloc(4ull * 1024 * 1024 * 2);
  ushort* upT    = (ushort*)alloc(4ull * 8192 * 1024 * 2);
  ushort* downT  = (ushort*)alloc(4ull * 1024 * 4096 * 2);
  ushort* vocabT = (ushort*)alloc(32000ull * 1024 * 2);

  const dim3 tb(32, 8);
  for (int l = 0; l < 4; ++l) {
    transpose_conv_kernel<<<dim3(3072 / 32, 1024 / 32), tb, 0, stream>>>(
        qkv_w + (size_t)l * 1024 * 3072, qkvT + (size_t)l * 3072 * 1024, 1024, 3072);
    transpose_conv_kernel<<<dim3(1024 / 32, 1024 / 32), tb, 0, stream>>>(
        out_w + (size_t)l * 1024 * 1024, outT + (size_t)l * 1024 * 1024, 1024, 1024);
    transpose_conv_kernel<<<dim3(8192 / 32, 1024 / 32), tb, 0, stream>>>(
        up_w + (size_t)l * 1024 * 8192, upT + (size_t)l * 8192 * 1024, 1024, 8192);
    transpose_conv_kernel<<<dim3(1024 / 32, 4096 / 32), tb, 0, stream>>>(
        down_w + (size_t)l * 4096 * 1024, downT + (size_t)l * 1024 * 4096, 4096, 1024);
  }
  transpose_conv_kernel<<<dim3(32000 / 32, 1024 / 32), tb, 0, stream>>>(
      vocab_w, vocabT, 1024, 32000);

  embed_kernel<<<2048, 256, 0, stream>>>(tokens, table, emb);

  for (int l = 0; l < 4; ++l) {
    rmsnorm_kernel<<<2048, 256, 0, stream>>>(emb, normed);
    gemm_bt_kernel<64, 128, 0><<<dim3(3072 / 128, 2048 / 64), 256, 0, stream>>>(
        normed, qkvT + (size_t)l * 3072 * 1024, nullptr, qkvbuf, 2048, 3072, 1024);
    rope_kernel<<<2048, 256, 0, stream>>>(qkvbuf, qhf, khf, vhf);
    attn_kernel<<<dim3(512, 16), 256, 0, stream>>>(qhf, khf, vhf, attno);
    gemm_bt_kernel<64, 128, 1><<<dim3(1024 / 128, 2048 / 64), 256, 0, stream>>>(
        attno, outT + (size_t)l * 1024 * 1024, emb, emb, 2048, 1024, 1024);
    rmsnorm_kernel<<<2048, 256, 0, stream>>>(emb, normed);
    gemm_bt_kernel<128, 128, 2><<<dim3(8192 / 128, 2048 / 128), 256, 0, stream>>>(
        normed, upT + (size_t)l * 8192 * 1024, nullptr, gateup, 2048, 8192, 1024);
    silu_mul_kernel<<<8192, 256, 0, stream>>>(gateup, hbuf);
    gemm_bt_kernel<64, 128, 1><<<dim3(1024 / 128, 2048 / 64), 256, 0, stream>>>(
        hbuf, downT + (size_t)l * 1024 * 4096, emb, emb, 2048, 1024, 4096);
  }
  rmsnorm_kernel<<<2048, 256, 0, stream>>>(emb, normed);
  gemm_bt_kernel<128, 128, 0><<<dim3(32000 / 128, 2048 / 128), 256, 0, stream>>>(
      normed, vocabT, nullptr, logits, 2048, 32000, 1024);
}

// Round 2
// 1452.126 us; speedup vs baseline: 2.2484x; 2.2484x over previous
//
#include <hip/hip_runtime.h>
#include <hip/hip_bf16.h>

// ---------- types ----------
typedef __attribute__((ext_vector_type(8))) short short8;   // 8 x bf16 bits
typedef __attribute__((ext_vector_type(4))) float f32x4;

__device__ __forceinline__ ushort f2bf(float f) {
  uint32_t u = __float_as_uint(f);
  uint32_t r = (u + 0x7FFFu + ((u >> 16) & 1u)) >> 16;
  return (ushort)r;
}
__device__ __forceinline__ float bf2f(ushort u) {
  return __uint_as_float(((uint32_t)u) << 16);
}

__device__ __forceinline__ void gload_lds16(const ushort* g, ushort* l) {
  __builtin_amdgcn_global_load_lds(
      (const __attribute__((address_space(1))) void*)g,
      (__attribute__((address_space(3))) void*)l, 16, 0, 0);
}

__device__ __forceinline__ f32x4 mfma16(short8 a, short8 b, f32x4 c) {
  return __builtin_amdgcn_mfma_f32_16x16x32_bf16(a, b, c, 0, 0, 0);
}

// ---------- transpose + fp32->bf16 convert: W[K][N] -> WT[N][K] ----------
__global__ __launch_bounds__(256)
void transpose_conv_kernel(const float* __restrict__ W, ushort* __restrict__ WT,
                           const int K, const int N) {
  __shared__ float tile[32][33];
  const int n0 = blockIdx.x * 32;
  const int k0 = blockIdx.y * 32;
  const int x = threadIdx.x;   // 0..31
  const int y = threadIdx.y;   // 0..7
#pragma unroll
  for (int j = 0; j < 4; ++j)
    tile[y + j * 8][x] = W[(size_t)(k0 + y + j * 8) * N + n0 + x];
  __syncthreads();
#pragma unroll
  for (int j = 0; j < 4; ++j)
    WT[(size_t)(n0 + y + j * 8) * K + k0 + x] = f2bf(tile[x][y + j * 8]);
}

// ---------- embedding gather (table row 0 forced to zero) ----------
__global__ __launch_bounds__(256)
void embed_kernel(const int* __restrict__ tokens, const float* __restrict__ table,
                  float* __restrict__ emb) {
  const int s = blockIdx.x, t = threadIdx.x;
  const int tok = tokens[s];
  float4 v = make_float4(0.f, 0.f, 0.f, 0.f);
  if (tok != 0) v = *(const float4*)&table[(size_t)tok * 1024 + t * 4];
  *(float4*)&emb[(size_t)s * 1024 + t * 4] = v;
}

// ---------- rmsnorm over 1024 cols: f32 in -> bf16 out ----------
__global__ __launch_bounds__(256)
void rmsnorm_kernel(const float* __restrict__ x, ushort* __restrict__ out) {
  const int row = blockIdx.x, t = threadIdx.x;
  const float4 v = *(const float4*)&x[(size_t)row * 1024 + t * 4];
  float ss = v.x * v.x + v.y * v.y + v.z * v.z + v.w * v.w;
#pragma unroll
  for (int off = 32; off; off >>= 1) ss += __shfl_xor(ss, off);
  __shared__ float red[4];
  if ((t & 63) == 0) red[t >> 6] = ss;
  __syncthreads();
  const float total = red[0] + red[1] + red[2] + red[3];
  const float sc = rsqrtf(total * (1.f / 1024.f) + 1e-5f);
  ushort4 o;
  o.x = f2bf(v.x * sc); o.y = f2bf(v.y * sc);
  o.z = f2bf(v.z * sc); o.w = f2bf(v.w * sc);
  *(ushort4*)&out[(size_t)row * 1024 + t * 4] = o;
}

// ---------- RoPE: qkv[s][3072] f32 -> qh/kh [h][s][64] bf16 ----------
__global__ __launch_bounds__(256)
void rope_kernel(const float* __restrict__ qkv, ushort* __restrict__ qh,
                 ushort* __restrict__ kh) {
  const int s = blockIdx.x;
  const int t = threadIdx.x;
  const int e0 = t * 4;            // element in [0,1024)
  const int hh = e0 >> 6;
  const int d0 = e0 & 63;
  const float* row = qkv + (size_t)s * 3072;
  const int part = hh * 64 + ((d0 + 32) & 63);
  const float4 xq  = *(const float4*)&row[e0];
  const float4 xqs = *(const float4*)&row[part];
  const float4 xk  = *(const float4*)&row[1024 + e0];
  const float4 xks = *(const float4*)&row[1024 + part];
  float co[4], si[4];
#pragma unroll
  for (int c = 0; c < 4; ++c) {
    const int d = d0 + c;
    const int off = d & 31;
    const float freq = exp2f(-0.41524101186092029f * (float)off); // 10000^(-off/32)
    const float ang = (float)s * freq;
    co[c] = cosf(ang);
    const float sv = sinf(ang);
    si[c] = (d < 32) ? -sv : sv;
  }
  ushort4 oq, ok;
  oq.x = f2bf(co[0] * xq.x + si[0] * xqs.x);
  oq.y = f2bf(co[1] * xq.y + si[1] * xqs.y);
  oq.z = f2bf(co[2] * xq.z + si[2] * xqs.z);
  oq.w = f2bf(co[3] * xq.w + si[3] * xqs.w);
  ok.x = f2bf(co[0] * xk.x + si[0] * xks.x);
  ok.y = f2bf(co[1] * xk.y + si[1] * xks.y);
  ok.z = f2bf(co[2] * xk.z + si[2] * xks.z);
  ok.w = f2bf(co[3] * xk.w + si[3] * xks.w);
  const size_t ho = ((size_t)hh * 2048 + s) * 64 + d0;
  *(ushort4*)&qh[ho] = oq;
  *(ushort4*)&kh[ho] = ok;
}

// ---------- V transpose: qkvbuf[s][2048+h*64+d] f32 -> vt[h][d][s] bf16 ----------
__global__ __launch_bounds__(256)
void vtrans_kernel(const float* __restrict__ qkvbuf, ushort* __restrict__ vt) {
  __shared__ float t[64][65];
  const int h = blockIdx.y;
  const int s0 = blockIdx.x * 64;
  const int tid = threadIdx.x;
#pragma unroll
  for (int j = 0; j < 4; ++j) {
    const int e = j * 1024 + tid * 4;
    const int r = e >> 6, c = e & 63;
    *(float4*)&t[r][c] = *(const float4*)&qkvbuf[(size_t)(s0 + r) * 3072 + 2048 + h * 64 + c];
  }
  __syncthreads();
#pragma unroll
  for (int j = 0; j < 4; ++j) {
    const int e = j * 1024 + tid * 4;
    const int d = e >> 6, s = e & 63;
    ushort4 ov;
    ov.x = f2bf(t[s + 0][d]);
    ov.y = f2bf(t[s + 1][d]);
    ov.z = f2bf(t[s + 2][d]);
    ov.w = f2bf(t[s + 3][d]);
    *(ushort4*)&vt[((size_t)h * 64 + d) * 2048 + s0 + s] = ov;
  }
}

// ---------- MFMA flash attention, causal; block = (64-row Q-tile, 1 head) ----------
// Swapped QK^T: S^T = mfma(A=K, B=Q)  (identical operand pattern to gemm_bt).
// LDS tiles [64][64] bf16, XOR-swizzled (16B chunk ^= row&7) via pre-swizzled
// global_load_lds sources. P re-shaped via wave-private swizzled LDS.
__global__ __launch_bounds__(256)
void attn_mfma_kernel(const ushort* __restrict__ qh, const ushort* __restrict__ kh,
                      const ushort* __restrict__ vt, ushort* __restrict__ attn_out) {
  __shared__ ushort sQ[64 * 64];
  __shared__ ushort sK[64 * 64];
  __shared__ ushort sV[64 * 64];     // V^T: rows = d, cols = key
  __shared__ ushort sP[4][1024];     // per-wave P [16 qrow][64 key]
  const int h = blockIdx.y;
  const int bx = blockIdx.x;
  const int qt = (h < 8) ? bx : 31 - bx;   // causal load-balance pairing
  const int i0 = qt * 64;
  const int tid = threadIdx.x;
  const int w = tid >> 6, lane = tid & 63;
  const int llo = lane & 15, lhi = lane >> 4;
  const int lr = lane >> 3, lc = lane & 7;   // staging: row-in-region / chunk
  const ushort* qg = qh + ((size_t)h * 2048 + i0) * 64;
  const ushort* kg = kh + (size_t)h * 2048 * 64;
  const ushort* vg = vt + (size_t)h * 64 * 2048;

  // stage Q tile (swizzled source -> linear LDS = swizzled layout)
#pragma unroll
  for (int j = 0; j < 2; ++j) {
    const int r0 = (w * 2 + j) * 8;
    const int row = r0 + lr;
    gload_lds16(qg + (size_t)row * 64 + ((lc ^ (row & 7)) * 8), &sQ[r0 * 64]);
  }
  __syncthreads();
  const int qrow = w * 16 + llo;     // tile-local q row this lane owns (as N col)
  const short8 qf0 = *(const short8*)&sQ[qrow * 64 + ((lhi ^ (qrow & 7)) * 8)];
  const short8 qf1 = *(const short8*)&sQ[qrow * 64 + (((4 + lhi) ^ (qrow & 7)) * 8)];

  float m = -1e30f, lsum = 0.f;
  f32x4 o[4] = {};                   // out frags: col=d=nn*16+llo, row=qrow=lhi*4+r
  const int nch = qt + 1;
  for (int cb = 0; cb < nch; ++cb) {
    const int kb = cb * 64;
    __syncthreads();
#pragma unroll
    for (int j = 0; j < 2; ++j) {
      const int r0 = (w * 2 + j) * 8;
      const int row = r0 + lr;
      gload_lds16(kg + (size_t)(kb + row) * 64 + ((lc ^ (row & 7)) * 8), &sK[r0 * 64]);
      gload_lds16(vg + (size_t)row * 2048 + kb + ((lc ^ (row & 7)) * 8), &sV[r0 * 64]);
    }
    __syncthreads();

    // S^T = K . Q^T : frag f covers keys f*16..f*16+15; lane holds
    // (key = f*16 + lhi*4 + r, qcol = qrow)
    f32x4 st[4] = {};
#pragma unroll
    for (int ck = 0; ck < 2; ++ck) {
      const short8 qf = ck ? qf1 : qf0;
#pragma unroll
      for (int f = 0; f < 4; ++f) {
        const int key = f * 16 + llo;
        const short8 kf = *(const short8*)&sK[key * 64 + (((ck * 4 + lhi) ^ (key & 7)) * 8)];
        st[f] = mfma16(kf, qf, st[f]);
      }
    }

    // scale + causal mask (only the diagonal tile kb==i0 needs masking)
    float pv[4][4];
    const bool diag = (kb == i0);
#pragma unroll
    for (int f = 0; f < 4; ++f)
#pragma unroll
      for (int r = 0; r < 4; ++r) {
        float x = st[f][r] * 0.125f;
        if (diag && (f * 16 + lhi * 4 + r) > qrow) x = -1e30f;
        pv[f][r] = x;
      }
    // row (per qrow) online softmax: in-reg reduce 16, then xor 16/32
    float mr = pv[0][0];
#pragma unroll
    for (int f = 0; f < 4; ++f)
#pragma unroll
      for (int r = 0; r < 4; ++r) mr = fmaxf(mr, pv[f][r]);
    mr = fmaxf(mr, __shfl_xor(mr, 16));
    mr = fmaxf(mr, __shfl_xor(mr, 32));
    const float mnew = fmaxf(m, mr);
    const float scale = __expf(m - mnew);
    m = mnew;
    float rs = 0.f;
#pragma unroll
    for (int f = 0; f < 4; ++f)
#pragma unroll
      for (int r = 0; r < 4; ++r) {
        const float p = __expf(pv[f][r] - mnew);
        pv[f][r] = p;
        rs += p;
      }
    rs += __shfl_xor(rs, 16);
    rs += __shfl_xor(rs, 32);
    lsum = lsum * scale + rs;
    // rescale O: O rows are qrow = lhi*4+r -> gather scale from lane lhi*4+r
    float scr[4];
#pragma unroll
    for (int r = 0; r < 4; ++r) scr[r] = __shfl(scale, lhi * 4 + r);
#pragma unroll
    for (int nn = 0; nn < 4; ++nn)
#pragma unroll
      for (int r = 0; r < 4; ++r) o[nn][r] *= scr[r];

    // P -> wave-private swizzled LDS, reload as PV A-frags
    ushort* pw = sP[w];
#pragma unroll
    for (int f = 0; f < 4; ++f) {
      uint2 pk;
      pk.x = (uint)f2bf(pv[f][0]) | ((uint)f2bf(pv[f][1]) << 16);
      pk.y = (uint)f2bf(pv[f][2]) | ((uint)f2bf(pv[f][3]) << 16);
      *(uint2*)&pw[llo * 64 + ((f * 16 + lhi * 4) ^ ((llo & 7) << 3))] = pk;
    }
    const short8 pf0 = *(const short8*)&pw[llo * 64 + ((lhi ^ (llo & 7)) * 8)];
    const short8 pf1 = *(const short8*)&pw[llo * 64 + (((4 + lhi) ^ (llo & 7)) * 8)];

    // O += P . V   (A = P[qrow][key], B via V^T rows)
#pragma unroll
    for (int ck = 0; ck < 2; ++ck) {
      const short8 pf = ck ? pf1 : pf0;
#pragma unroll
      for (int nn = 0; nn < 4; ++nn) {
        const int drow = nn * 16 + llo;
        const short8 vf = *(const short8*)&sV[drow * 64 + (((ck * 4 + lhi) ^ (drow & 7)) * 8)];
        o[nn] = mfma16(pf, vf, o[nn]);
      }
    }
  }

  // epilogue: normalize and store bf16
  const float inv = 1.f / lsum;
  float invr[4];
#pragma unroll
  for (int r = 0; r < 4; ++r) invr[r] = __shfl(inv, lhi * 4 + r);
#pragma unroll
  for (int nn = 0; nn < 4; ++nn)
#pragma unroll
    for (int r = 0; r < 4; ++r) {
      const int row = i0 + w * 16 + lhi * 4 + r;
      attn_out[(size_t)row * 1024 + h * 64 + nn * 16 + llo] = f2bf(o[nn][r] * invr[r]);
    }
}

// ---------- SiLU(gate) * up : gateup[2048][8192] bf16 -> h[2048][4096] bf16 ----------
__global__ __launch_bounds__(256)
void silu_mul_kernel(const ushort* __restrict__ gu, ushort* __restrict__ hb) {
  const int idx = blockIdx.x * 256 + threadIdx.x;
  const int i = idx * 4;
  const int r = i >> 12;
  const int c = i & 4095;
  const ushort4 g4 = *(const ushort4*)&gu[(size_t)r * 8192 + c];
  const ushort4 u4 = *(const ushort4*)&gu[(size_t)r * 8192 + 4096 + c];
  ushort4 o;
  {
    float gv = bf2f(g4.x), uv = bf2f(u4.x);
    o.x = f2bf(uv * gv / (1.f + expf(-gv)));
  }
  {
    float gv = bf2f(g4.y), uv = bf2f(u4.y);
    o.y = f2bf(uv * gv / (1.f + expf(-gv)));
  }
  {
    float gv = bf2f(g4.z), uv = bf2f(u4.z);
    o.z = f2bf(uv * gv / (1.f + expf(-gv)));
  }
  {
    float gv = bf2f(g4.w), uv = bf2f(u4.w);
    o.w = f2bf(uv * gv / (1.f + expf(-gv)));
  }
  *(ushort4*)&hb[(size_t)r * 4096 + c] = o;
}

// ---------- bf16 MFMA GEMM: C[M][N] = A[M][K] * BT[N][K]^T (+ addend) ----------
// EPI: 0 = f32 store, 1 = f32 addend + store, 2 = bf16 store
template <int BM, int BN, int EPI>
__global__ __launch_bounds__(256)
void gemm_bt_kernel(const ushort* __restrict__ A, const ushort* __restrict__ BT,
                    const float* __restrict__ addend, void* __restrict__ Cout,
                    const int M, const int N, const int K) {
  constexpr int WM = BM / 2, WN = BN / 2;
  constexpr int FM = WM / 16, FN = WN / 16;
  constexpr int CHA = BM / 16, CHB = BN / 16;   // 1KB staging chunks
  __shared__ ushort sA[BM * 32];
  __shared__ ushort sB[BN * 32];
  const int bm0 = blockIdx.y * BM;
  const int bn0 = blockIdx.x * BN;
  const int tid = threadIdx.x;
  const int wid = tid >> 6;
  const int lane = tid & 63;
  const int wr = wid >> 1, wc = wid & 1;
  const int lhi = lane >> 4, llo = lane & 15;
  f32x4 acc[FM][FN] = {};
  for (int kt = 0; kt < K; kt += 32) {
#pragma unroll
    for (int c2 = 0; c2 < CHA / 4; ++c2) {
      const int ch = c2 * 4 + wid;
      const int e = ch * 512 + lane * 8;
      gload_lds16(A + (size_t)(bm0 + (e >> 5)) * K + kt + (e & 31), sA + ch * 512);
    }
#pragma unroll
    for (int c2 = 0; c2 < CHB / 4; ++c2) {
      const int ch = c2 * 4 + wid;
      const int e = ch * 512 + lane * 8;
      gload_lds16(BT + (size_t)(bn0 + (e >> 5)) * K + kt + (e & 31), sB + ch * 512);
    }
    __syncthreads();
    short8 aF[FM], bF[FN];
#pragma unroll
    for (int mm = 0; mm < FM; ++mm)
      aF[mm] = *(const short8*)&sA[(wr * WM + mm * 16 + llo) * 32 + lhi * 8];
#pragma unroll
    for (int nn = 0; nn < FN; ++nn)
      bF[nn] = *(const short8*)&sB[(wc * WN + nn * 16 + llo) * 32 + lhi * 8];
#pragma unroll
    for (int mm = 0; mm < FM; ++mm)
#pragma unroll
      for (int nn = 0; nn < FN; ++nn)
        acc[mm][nn] = __builtin_amdgcn_mfma_f32_16x16x32_bf16(aF[mm], bF[nn],
                                                              acc[mm][nn], 0, 0, 0);
    __syncthreads();
  }
  // epilogue: C/D layout col = lane&15, row = (lane>>4)*4 + reg
#pragma unroll
  for (int mm = 0; mm < FM; ++mm) {
#pragma unroll
    for (int nn = 0; nn < FN; ++nn) {
      const int col = bn0 + wc * WN + nn * 16 + llo;
#pragma unroll
      for (int r = 0; r < 4; ++r) {
        const int row = bm0 + wr * WM + mm * 16 + lhi * 4 + r;
        float v = acc[mm][nn][r];
        if constexpr (EPI == 2) {
          ((ushort*)Cout)[(size_t)row * N + col] = f2bf(v);
        } else {
          if constexpr (EPI == 1) v += addend[(size_t)row * N + col];
          ((float*)Cout)[(size_t)row * N + col] = v;
        }
      }
    }
  }
}

// ---------- launch ----------
extern "C" void kernel_launch(void* const* d_in, const int* in_sizes, int n_in,
                              void* d_out, int out_size, void* d_ws, size_t ws_size,
                              hipStream_t stream) {
  const int* tokens    = (const int*)d_in[0];
  const float* table   = (const float*)d_in[1];
  const float* qkv_w   = (const float*)d_in[2];
  const float* out_w   = (const float*)d_in[3];
  const float* up_w    = (const float*)d_in[4];
  const float* down_w  = (const float*)d_in[5];
  const float* vocab_w = (const float*)d_in[6];
  float* logits = (float*)d_out;

  char* p = (char*)d_ws;
  auto alloc = [&](size_t bytes) {
    char* r = p;
    p += (bytes + 255) & ~(size_t)255;
    return r;
  };
  float*  emb    = (float*)alloc(2048ull * 1024 * 4);
  ushort* normed = (ushort*)alloc(2048ull * 1024 * 2);
  float*  qkvbuf = (float*)alloc(2048ull * 3072 * 4);
  ushort* qhb    = (ushort*)alloc(16ull * 2048 * 64 * 2);
  ushort* khb    = (ushort*)alloc(16ull * 2048 * 64 * 2);
  ushort* vtb    = (ushort*)alloc(16ull * 64 * 2048 * 2);
  ushort* attno  = (ushort*)alloc(2048ull * 1024 * 2);
  ushort* gateup = (ushort*)alloc(2048ull * 8192 * 2);
  ushort* hbuf   = (ushort*)alloc(2048ull * 4096 * 2);
  ushort* qkvT   = (ushort*)alloc(4ull * 3072 * 1024 * 2);
  ushort* outT   = (ushort*)alloc(4ull * 1024 * 1024 * 2);
  ushort* upT    = (ushort*)alloc(4ull * 8192 * 1024 * 2);
  ushort* downT  = (ushort*)alloc(4ull * 1024 * 4096 * 2);
  ushort* vocabT = (ushort*)alloc(32000ull * 1024 * 2);

  const dim3 tb(32, 8);
  for (int l = 0; l < 4; ++l) {
    transpose_conv_kernel<<<dim3(3072 / 32, 1024 / 32), tb, 0, stream>>>(
        qkv_w + (size_t)l * 1024 * 3072, qkvT + (size_t)l * 3072 * 1024, 1024, 3072);
    transpose_conv_kernel<<<dim3(1024 / 32, 1024 / 32), tb, 0, stream>>>(
        out_w + (size_t)l * 1024 * 1024, outT + (size_t)l * 1024 * 1024, 1024, 1024);
    transpose_conv_kernel<<<dim3(8192 / 32, 1024 / 32), tb, 0, stream>>>(
        up_w + (size_t)l * 1024 * 8192, upT + (size_t)l * 8192 * 1024, 1024, 8192);
    transpose_conv_kernel<<<dim3(1024 / 32, 4096 / 32), tb, 0, stream>>>(
        down_w + (size_t)l * 4096 * 1024, downT + (size_t)l * 1024 * 4096, 4096, 1024);
  }
  transpose_conv_kernel<<<dim3(32000 / 32, 1024 / 32), tb, 0, stream>>>(
      vocab_w, vocabT, 1024, 32000);

  embed_kernel<<<2048, 256, 0, stream>>>(tokens, table, emb);

  for (int l = 0; l < 4; ++l) {
    rmsnorm_kernel<<<2048, 256, 0, stream>>>(emb, normed);
    gemm_bt_kernel<64, 128, 0><<<dim3(3072 / 128, 2048 / 64), 256, 0, stream>>>(
        normed, qkvT + (size_t)l * 3072 * 1024, nullptr, qkvbuf, 2048, 3072, 1024);
    rope_kernel<<<2048, 256, 0, stream>>>(qkvbuf, qhb, khb);
    vtrans_kernel<<<dim3(32, 16), 256, 0, stream>>>(qkvbuf, vtb);
    attn_mfma_kernel<<<dim3(32, 16), 256, 0, stream>>>(qhb, khb, vtb, attno);
    gemm_bt_kernel<64, 128, 1><<<dim3(1024 / 128, 2048 / 64), 256, 0, stream>>>(
        attno, outT + (size_t)l * 1024 * 1024, emb, emb, 2048, 1024, 1024);
    rmsnorm_kernel<<<2048, 256, 0, stream>>>(emb, normed);
    gemm_bt_kernel<128, 128, 2><<<dim3(8192 / 128, 2048 / 128), 256, 0, stream>>>(
        normed, upT + (size_t)l * 8192 * 1024, nullptr, gateup, 2048, 8192, 1024);
    silu_mul_kernel<<<8192, 256, 0, stream>>>(gateup, hbuf);
    gemm_bt_kernel<64, 128, 1><<<dim3(1024 / 128, 2048 / 64), 256, 0, stream>>>(
        hbuf, downT + (size_t)l * 1024 * 4096, emb, emb, 2048, 1024, 4096);
  }
  rmsnorm_kernel<<<2048, 256, 0, stream>>>(emb, normed);
  gemm_bt_kernel<128, 128, 0><<<dim3(32000 / 128, 2048 / 128), 256, 0, stream>>>(
      normed, vocabT, nullptr, logits, 2048, 32000, 1024);
}

// Round 3
// 1384.114 us; speedup vs baseline: 2.3589x; 1.0491x over previous
//
#include <hip/hip_runtime.h>
#include <hip/hip_bf16.h>

// ---------- types ----------
typedef __attribute__((ext_vector_type(8))) short short8;   // 8 x bf16 bits
typedef __attribute__((ext_vector_type(4))) float f32x4;

__device__ __forceinline__ ushort f2bf(float f) {
  uint32_t u = __float_as_uint(f);
  uint32_t r = (u + 0x7FFFu + ((u >> 16) & 1u)) >> 16;
  return (ushort)r;
}
__device__ __forceinline__ float bf2f(ushort u) {
  return __uint_as_float(((uint32_t)u) << 16);
}

__device__ __forceinline__ void gload_lds16(const ushort* g, ushort* l) {
  __builtin_amdgcn_global_load_lds(
      (const __attribute__((address_space(1))) void*)g,
      (__attribute__((address_space(3))) void*)l, 16, 0, 0);
}

__device__ __forceinline__ f32x4 mfma16(short8 a, short8 b, f32x4 c) {
  return __builtin_amdgcn_mfma_f32_16x16x32_bf16(a, b, c, 0, 0, 0);
}

#define BAR() __builtin_amdgcn_s_barrier()
#define WAIT_LGKM()                                        \
  do {                                                     \
    asm volatile("s_waitcnt lgkmcnt(0)" ::: "memory");     \
    __builtin_amdgcn_sched_barrier(0);                     \
  } while (0)
#define WAIT_VM()                                          \
  do {                                                     \
    asm volatile("s_waitcnt vmcnt(0)" ::: "memory");       \
    __builtin_amdgcn_sched_barrier(0);                     \
  } while (0)

// ---------- transpose + fp32->bf16 convert: W[K][N] -> WT[N][K] ----------
__global__ __launch_bounds__(256)
void transpose_conv_kernel(const float* __restrict__ W, ushort* __restrict__ WT,
                           const int K, const int N) {
  __shared__ float tile[32][33];
  const int n0 = blockIdx.x * 32;
  const int k0 = blockIdx.y * 32;
  const int x = threadIdx.x;   // 0..31
  const int y = threadIdx.y;   // 0..7
#pragma unroll
  for (int j = 0; j < 4; ++j)
    tile[y + j * 8][x] = W[(size_t)(k0 + y + j * 8) * N + n0 + x];
  __syncthreads();
#pragma unroll
  for (int j = 0; j < 4; ++j)
    WT[(size_t)(n0 + y + j * 8) * K + k0 + x] = f2bf(tile[x][y + j * 8]);
}

// ---------- embedding gather (table row 0 forced to zero) ----------
__global__ __launch_bounds__(256)
void embed_kernel(const int* __restrict__ tokens, const float* __restrict__ table,
                  float* __restrict__ emb) {
  const int s = blockIdx.x, t = threadIdx.x;
  const int tok = tokens[s];
  float4 v = make_float4(0.f, 0.f, 0.f, 0.f);
  if (tok != 0) v = *(const float4*)&table[(size_t)tok * 1024 + t * 4];
  *(float4*)&emb[(size_t)s * 1024 + t * 4] = v;
}

// ---------- rmsnorm over 1024 cols: f32 in -> bf16 out ----------
__global__ __launch_bounds__(256)
void rmsnorm_kernel(const float* __restrict__ x, ushort* __restrict__ out) {
  const int row = blockIdx.x, t = threadIdx.x;
  const float4 v = *(const float4*)&x[(size_t)row * 1024 + t * 4];
  float ss = v.x * v.x + v.y * v.y + v.z * v.z + v.w * v.w;
#pragma unroll
  for (int off = 32; off; off >>= 1) ss += __shfl_xor(ss, off);
  __shared__ float red[4];
  if ((t & 63) == 0) red[t >> 6] = ss;
  __syncthreads();
  const float total = red[0] + red[1] + red[2] + red[3];
  const float sc = rsqrtf(total * (1.f / 1024.f) + 1e-5f);
  ushort4 o;
  o.x = f2bf(v.x * sc); o.y = f2bf(v.y * sc);
  o.z = f2bf(v.z * sc); o.w = f2bf(v.w * sc);
  *(ushort4*)&out[(size_t)row * 1024 + t * 4] = o;
}

// ---------- RoPE: qkv[s][3072] f32 -> qh/kh [h][s][64] bf16 ----------
__global__ __launch_bounds__(256)
void rope_kernel(const float* __restrict__ qkv, ushort* __restrict__ qh,
                 ushort* __restrict__ kh) {
  const int s = blockIdx.x;
  const int t = threadIdx.x;
  const int e0 = t * 4;            // element in [0,1024)
  const int hh = e0 >> 6;
  const int d0 = e0 & 63;
  const float* row = qkv + (size_t)s * 3072;
  const int part = hh * 64 + ((d0 + 32) & 63);
  const float4 xq  = *(const float4*)&row[e0];
  const float4 xqs = *(const float4*)&row[part];
  const float4 xk  = *(const float4*)&row[1024 + e0];
  const float4 xks = *(const float4*)&row[1024 + part];
  float co[4], si[4];
#pragma unroll
  for (int c = 0; c < 4; ++c) {
    const int d = d0 + c;
    const int off = d & 31;
    const float freq = exp2f(-0.41524101186092029f * (float)off); // 10000^(-off/32)
    const float ang = (float)s * freq;
    co[c] = cosf(ang);
    const float sv = sinf(ang);
    si[c] = (d < 32) ? -sv : sv;
  }
  ushort4 oq, ok;
  oq.x = f2bf(co[0] * xq.x + si[0] * xqs.x);
  oq.y = f2bf(co[1] * xq.y + si[1] * xqs.y);
  oq.z = f2bf(co[2] * xq.z + si[2] * xqs.z);
  oq.w = f2bf(co[3] * xq.w + si[3] * xqs.w);
  ok.x = f2bf(co[0] * xk.x + si[0] * xks.x);
  ok.y = f2bf(co[1] * xk.y + si[1] * xks.y);
  ok.z = f2bf(co[2] * xk.z + si[2] * xks.z);
  ok.w = f2bf(co[3] * xk.w + si[3] * xks.w);
  const size_t ho = ((size_t)hh * 2048 + s) * 64 + d0;
  *(ushort4*)&qh[ho] = oq;
  *(ushort4*)&kh[ho] = ok;
}

// ---------- V transpose: qkvbuf[s][2048+h*64+d] f32 -> vt[h][d][s] bf16 ----------
__global__ __launch_bounds__(256)
void vtrans_kernel(const float* __restrict__ qkvbuf, ushort* __restrict__ vt) {
  __shared__ float t[64][65];
  const int h = blockIdx.y;
  const int s0 = blockIdx.x * 64;
  const int tid = threadIdx.x;
#pragma unroll
  for (int j = 0; j < 4; ++j) {
    const int e = j * 1024 + tid * 4;
    const int r = e >> 6, c = e & 63;
    *(float4*)&t[r][c] = *(const float4*)&qkvbuf[(size_t)(s0 + r) * 3072 + 2048 + h * 64 + c];
  }
  __syncthreads();
#pragma unroll
  for (int j = 0; j < 4; ++j) {
    const int e = j * 1024 + tid * 4;
    const int d = e >> 6, s = e & 63;
    ushort4 ov;
    ov.x = f2bf(t[s + 0][d]);
    ov.y = f2bf(t[s + 1][d]);
    ov.z = f2bf(t[s + 2][d]);
    ov.w = f2bf(t[s + 3][d]);
    *(ushort4*)&vt[((size_t)h * 64 + d) * 2048 + s0 + s] = ov;
  }
}

// ---------- MFMA flash attention, causal; block = (64-row Q-tile, 1 head) ----------
__global__ __launch_bounds__(256)
void attn_mfma_kernel(const ushort* __restrict__ qh, const ushort* __restrict__ kh,
                      const ushort* __restrict__ vt, ushort* __restrict__ attn_out) {
  __shared__ ushort sQ[64 * 64];
  __shared__ ushort sK[64 * 64];
  __shared__ ushort sV[64 * 64];     // V^T: rows = d, cols = key
  __shared__ ushort sP[4][1024];     // per-wave P [16 qrow][64 key]
  const int h = blockIdx.y;
  const int bx = blockIdx.x;
  const int qt = (h < 8) ? bx : 31 - bx;   // causal load-balance pairing
  const int i0 = qt * 64;
  const int tid = threadIdx.x;
  const int w = tid >> 6, lane = tid & 63;
  const int llo = lane & 15, lhi = lane >> 4;
  const int lr = lane >> 3, lc = lane & 7;   // staging: row-in-region / chunk
  const ushort* qg = qh + ((size_t)h * 2048 + i0) * 64;
  const ushort* kg = kh + (size_t)h * 2048 * 64;
  const ushort* vg = vt + (size_t)h * 64 * 2048;

#pragma unroll
  for (int j = 0; j < 2; ++j) {
    const int r0 = (w * 2 + j) * 8;
    const int row = r0 + lr;
    gload_lds16(qg + (size_t)row * 64 + ((lc ^ (row & 7)) * 8), &sQ[r0 * 64]);
  }
  __syncthreads();
  const int qrow = w * 16 + llo;     // tile-local q row this lane owns (as N col)
  const short8 qf0 = *(const short8*)&sQ[qrow * 64 + ((lhi ^ (qrow & 7)) * 8)];
  const short8 qf1 = *(const short8*)&sQ[qrow * 64 + (((4 + lhi) ^ (qrow & 7)) * 8)];

  float m = -1e30f, lsum = 0.f;
  f32x4 o[4] = {};                   // out frags: col=d=nn*16+llo, row=qrow=lhi*4+r
  const int nch = qt + 1;
  for (int cb = 0; cb < nch; ++cb) {
    const int kb = cb * 64;
    __syncthreads();
#pragma unroll
    for (int j = 0; j < 2; ++j) {
      const int r0 = (w * 2 + j) * 8;
      const int row = r0 + lr;
      gload_lds16(kg + (size_t)(kb + row) * 64 + ((lc ^ (row & 7)) * 8), &sK[r0 * 64]);
      gload_lds16(vg + (size_t)row * 2048 + kb + ((lc ^ (row & 7)) * 8), &sV[r0 * 64]);
    }
    __syncthreads();

    f32x4 st[4] = {};
#pragma unroll
    for (int ck = 0; ck < 2; ++ck) {
      const short8 qf = ck ? qf1 : qf0;
#pragma unroll
      for (int f = 0; f < 4; ++f) {
        const int key = f * 16 + llo;
        const short8 kf = *(const short8*)&sK[key * 64 + (((ck * 4 + lhi) ^ (key & 7)) * 8)];
        st[f] = mfma16(kf, qf, st[f]);
      }
    }

    float pv[4][4];
    const bool diag = (kb == i0);
#pragma unroll
    for (int f = 0; f < 4; ++f)
#pragma unroll
      for (int r = 0; r < 4; ++r) {
        float x = st[f][r] * 0.125f;
        if (diag && (f * 16 + lhi * 4 + r) > qrow) x = -1e30f;
        pv[f][r] = x;
      }
    float mr = pv[0][0];
#pragma unroll
    for (int f = 0; f < 4; ++f)
#pragma unroll
      for (int r = 0; r < 4; ++r) mr = fmaxf(mr, pv[f][r]);
    mr = fmaxf(mr, __shfl_xor(mr, 16));
    mr = fmaxf(mr, __shfl_xor(mr, 32));
    const float mnew = fmaxf(m, mr);
    const float scale = __expf(m - mnew);
    m = mnew;
    float rs = 0.f;
#pragma unroll
    for (int f = 0; f < 4; ++f)
#pragma unroll
      for (int r = 0; r < 4; ++r) {
        const float p = __expf(pv[f][r] - mnew);
        pv[f][r] = p;
        rs += p;
      }
    rs += __shfl_xor(rs, 16);
    rs += __shfl_xor(rs, 32);
    lsum = lsum * scale + rs;
    float scr[4];
#pragma unroll
    for (int r = 0; r < 4; ++r) scr[r] = __shfl(scale, lhi * 4 + r);
#pragma unroll
    for (int nn = 0; nn < 4; ++nn)
#pragma unroll
      for (int r = 0; r < 4; ++r) o[nn][r] *= scr[r];

    ushort* pw = sP[w];
#pragma unroll
    for (int f = 0; f < 4; ++f) {
      uint2 pk;
      pk.x = (uint)f2bf(pv[f][0]) | ((uint)f2bf(pv[f][1]) << 16);
      pk.y = (uint)f2bf(pv[f][2]) | ((uint)f2bf(pv[f][3]) << 16);
      *(uint2*)&pw[llo * 64 + ((f * 16 + lhi * 4) ^ ((llo & 7) << 3))] = pk;
    }
    const short8 pf0 = *(const short8*)&pw[llo * 64 + ((lhi ^ (llo & 7)) * 8)];
    const short8 pf1 = *(const short8*)&pw[llo * 64 + (((4 + lhi) ^ (llo & 7)) * 8)];

#pragma unroll
    for (int ck = 0; ck < 2; ++ck) {
      const short8 pf = ck ? pf1 : pf0;
#pragma unroll
      for (int nn = 0; nn < 4; ++nn) {
        const int drow = nn * 16 + llo;
        const short8 vf = *(const short8*)&sV[drow * 64 + (((ck * 4 + lhi) ^ (drow & 7)) * 8)];
        o[nn] = mfma16(pf, vf, o[nn]);
      }
    }
  }

  const float inv = 1.f / lsum;
  float invr[4];
#pragma unroll
  for (int r = 0; r < 4; ++r) invr[r] = __shfl(inv, lhi * 4 + r);
#pragma unroll
  for (int nn = 0; nn < 4; ++nn)
#pragma unroll
    for (int r = 0; r < 4; ++r) {
      const int row = i0 + w * 16 + lhi * 4 + r;
      attn_out[(size_t)row * 1024 + h * 64 + nn * 16 + llo] = f2bf(o[nn][r] * invr[r]);
    }
}

// ---------- SiLU(gate) * up : gateup[2048][8192] bf16 -> h[2048][4096] bf16 ----------
__global__ __launch_bounds__(256)
void silu_mul_kernel(const ushort* __restrict__ gu, ushort* __restrict__ hb) {
  const int idx = blockIdx.x * 256 + threadIdx.x;
  const int i = idx * 4;
  const int r = i >> 12;
  const int c = i & 4095;
  const ushort4 g4 = *(const ushort4*)&gu[(size_t)r * 8192 + c];
  const ushort4 u4 = *(const ushort4*)&gu[(size_t)r * 8192 + 4096 + c];
  ushort4 o;
  {
    float gv = bf2f(g4.x), uv = bf2f(u4.x);
    o.x = f2bf(uv * gv / (1.f + expf(-gv)));
  }
  {
    float gv = bf2f(g4.y), uv = bf2f(u4.y);
    o.y = f2bf(uv * gv / (1.f + expf(-gv)));
  }
  {
    float gv = bf2f(g4.z), uv = bf2f(u4.z);
    o.z = f2bf(uv * gv / (1.f + expf(-gv)));
  }
  {
    float gv = bf2f(g4.w), uv = bf2f(u4.w);
    o.w = f2bf(uv * gv / (1.f + expf(-gv)));
  }
  *(ushort4*)&hb[(size_t)r * 4096 + c] = o;
}

// ---------- 2-phase bf16 MFMA GEMM (small-N shapes): C = A * BT^T (+addend) ----------
template <int BM, int BN, int EPI>
__global__ __launch_bounds__(256)
void gemm_bt_kernel(const ushort* __restrict__ A, const ushort* __restrict__ BT,
                    const float* __restrict__ addend, void* __restrict__ Cout,
                    const int M, const int N, const int K) {
  constexpr int WM = BM / 2, WN = BN / 2;
  constexpr int FM = WM / 16, FN = WN / 16;
  constexpr int CHA = BM / 16, CHB = BN / 16;   // 1KB staging chunks
  __shared__ ushort sA[BM * 32];
  __shared__ ushort sB[BN * 32];
  const int bm0 = blockIdx.y * BM;
  const int bn0 = blockIdx.x * BN;
  const int tid = threadIdx.x;
  const int wid = tid >> 6;
  const int lane = tid & 63;
  const int wr = wid >> 1, wc = wid & 1;
  const int lhi = lane >> 4, llo = lane & 15;
  f32x4 acc[FM][FN] = {};
  for (int kt = 0; kt < K; kt += 32) {
#pragma unroll
    for (int c2 = 0; c2 < CHA / 4; ++c2) {
      const int ch = c2 * 4 + wid;
      const int e = ch * 512 + lane * 8;
      gload_lds16(A + (size_t)(bm0 + (e >> 5)) * K + kt + (e & 31), sA + ch * 512);
    }
#pragma unroll
    for (int c2 = 0; c2 < CHB / 4; ++c2) {
      const int ch = c2 * 4 + wid;
      const int e = ch * 512 + lane * 8;
      gload_lds16(BT + (size_t)(bn0 + (e >> 5)) * K + kt + (e & 31), sB + ch * 512);
    }
    __syncthreads();
    short8 aF[FM], bF[FN];
#pragma unroll
    for (int mm = 0; mm < FM; ++mm)
      aF[mm] = *(const short8*)&sA[(wr * WM + mm * 16 + llo) * 32 + lhi * 8];
#pragma unroll
    for (int nn = 0; nn < FN; ++nn)
      bF[nn] = *(const short8*)&sB[(wc * WN + nn * 16 + llo) * 32 + lhi * 8];
#pragma unroll
    for (int mm = 0; mm < FM; ++mm)
#pragma unroll
      for (int nn = 0; nn < FN; ++nn)
        acc[mm][nn] = __builtin_amdgcn_mfma_f32_16x16x32_bf16(aF[mm], bF[nn],
                                                              acc[mm][nn], 0, 0, 0);
    __syncthreads();
  }
#pragma unroll
  for (int mm = 0; mm < FM; ++mm) {
#pragma unroll
    for (int nn = 0; nn < FN; ++nn) {
      const int col = bn0 + wc * WN + nn * 16 + llo;
#pragma unroll
      for (int r = 0; r < 4; ++r) {
        const int row = bm0 + wr * WM + mm * 16 + lhi * 4 + r;
        float v = acc[mm][nn][r];
        if constexpr (EPI == 2) {
          ((ushort*)Cout)[(size_t)row * N + col] = f2bf(v);
        } else {
          if constexpr (EPI == 1) v += addend[(size_t)row * N + col];
          ((float*)Cout)[(size_t)row * N + col] = v;
        }
      }
    }
  }
}

// ---------- 8-phase 256x256 BK=64 double-buffered GEMM (T2+T3+T4+T5) ----------
// C[M][N] = A[M][K] * BT[N][K]^T. 512 threads = 8 waves (2M x 4N), per-wave
// 128x64 output (acc[8][4]). LDS 128KB dynamic: 2 bufs x (A 256x64 + B 256x64)
// bf16, XOR row-swizzle at 16B-chunk granularity (both-sides: pre-swizzled
// global_load_lds source + swizzled ds_read). Raw s_barrier + counted waits;
// next K-tile staged in phase 0, drained once at phase 3 (~3 phases of cover).
// Grid: 1D, nbx*nby blocks, %8==0 required (bijective XCD swizzle).
#define LDA_(MH)                                                              \
  {                                                                           \
    _Pragma("unroll") for (int mm = 0; mm < 4; ++mm) {                        \
      const int row = wr * 128 + ((MH) * 4 + mm) * 16 + llo;                  \
      _Pragma("unroll") for (int ks = 0; ks < 2; ++ks)                        \
          aF[mm][ks] = *(const short8*)&cA[row * 64 +                         \
                          (((ks * 4 + lhi) ^ (row & 7)) * 8)];                \
    }                                                                         \
  }
#define LDB_(NH)                                                              \
  {                                                                           \
    _Pragma("unroll") for (int nn = 0; nn < 2; ++nn) {                        \
      const int row = wc * 64 + ((NH) * 2 + nn) * 16 + llo;                   \
      _Pragma("unroll") for (int ks = 0; ks < 2; ++ks)                        \
          bF[nn][ks] = *(const short8*)&cB[row * 64 +                         \
                          (((ks * 4 + lhi) ^ (row & 7)) * 8)];                \
    }                                                                         \
  }
#define MFMAQ_(MH, NH)                                                        \
  {                                                                           \
    __builtin_amdgcn_s_setprio(1);                                            \
    _Pragma("unroll") for (int mm = 0; mm < 4; ++mm)                          \
        _Pragma("unroll") for (int nn = 0; nn < 2; ++nn)                      \
            _Pragma("unroll") for (int ks = 0; ks < 2; ++ks)                  \
                acc[(MH) * 4 + mm][(NH) * 2 + nn] =                           \
                    mfma16(aF[mm][ks], bF[nn][ks],                            \
                           acc[(MH) * 4 + mm][(NH) * 2 + nn]);                \
    __builtin_amdgcn_s_setprio(0);                                            \
  }

template <int EPI>
__global__ __launch_bounds__(512, 2)
void gemm8_kernel(const ushort* __restrict__ A, const ushort* __restrict__ BT,
                  const float* __restrict__ addend, void* __restrict__ Cout,
                  const int M, const int N, const int K, const int nbx) {
  extern __shared__ ushort smem[];   // [2][A 16384 | B 16384]
  const int nwg = gridDim.x;
  const int cpx = nwg >> 3;
  int id = blockIdx.x;
  id = (id & 7) * cpx + (id >> 3);   // bijective XCD swizzle (nwg%8==0)
  const int bx = id % nbx, by = id / nbx;
  const int bm0 = by * 256, bn0 = bx * 256;
  const int tid = threadIdx.x;
  const int wid = tid >> 6, lane = tid & 63;
  const int wr = wid >> 2, wc = wid & 3;
  const int llo = lane & 15, lhi = lane >> 4;
  const ushort* gA = A + (size_t)bm0 * K;
  const ushort* gB = BT + (size_t)bn0 * K;

  // stage one 256x64 operand tile; LDS dest linear, global source pre-swizzled
  auto stage = [&](const ushort* g, ushort* dst, int kt) {
#pragma unroll
    for (int i = 0; i < 4; ++i) {
      const int chunk = i * 512 + wid * 64 + lane;
      const int row = chunk >> 3, c = chunk & 7;
      gload_lds16(g + (size_t)row * K + kt + ((c ^ (row & 7)) * 8),
                  dst + (size_t)(i * 512 + wid * 64) * 8);
    }
  };

  f32x4 acc[8][4] = {};
  short8 aF[4][2];
  short8 bF[2][2];

  stage(gA, smem, 0);
  stage(gB, smem + 16384, 0);
  WAIT_VM();
  BAR();

  const int nt = K >> 6;
  for (int t = 0; t < nt; ++t) {
    const int cur = t & 1;
    ushort* cA = smem + cur * 32768;
    ushort* cB = cA + 16384;
    ushort* nA = smem + (cur ^ 1) * 32768;
    ushort* nB = nA + 16384;
    const bool pf = (t + 1 < nt);
    // phase 0: quadrant (0,0); issue all next-tile loads
    LDA_(0); LDB_(0);
    if (pf) { stage(gA, nA, (t + 1) * 64); stage(gB, nB, (t + 1) * 64); }
    BAR(); WAIT_LGKM();
    MFMAQ_(0, 0);
    BAR();
    // phase 1: quadrant (0,1)
    LDB_(1);
    BAR(); WAIT_LGKM();
    MFMAQ_(0, 1);
    BAR();
    // phase 2: quadrant (1,1)
    LDA_(1);
    BAR(); WAIT_LGKM();
    MFMAQ_(1, 1);
    BAR();
    // phase 3: quadrant (1,0); drain prefetch before buffer swap
    LDB_(0);
    BAR(); WAIT_LGKM();
    MFMAQ_(1, 0);
    if (pf) WAIT_VM();
    BAR();
  }

  // epilogue: D row = A-side (lhi*4+r), col = B-side (llo)
#pragma unroll
  for (int m = 0; m < 8; ++m) {
#pragma unroll
    for (int n = 0; n < 4; ++n) {
      const int col = bn0 + wc * 64 + n * 16 + llo;
#pragma unroll
      for (int r = 0; r < 4; ++r) {
        const int row = bm0 + wr * 128 + m * 16 + lhi * 4 + r;
        float v = acc[m][n][r];
        if constexpr (EPI == 2) {
          ((ushort*)Cout)[(size_t)row * N + col] = f2bf(v);
        } else {
          if constexpr (EPI == 1) v += addend[(size_t)row * N + col];
          ((float*)Cout)[(size_t)row * N + col] = v;
        }
      }
    }
  }
}

// ---------- launch ----------
extern "C" void kernel_launch(void* const* d_in, const int* in_sizes, int n_in,
                              void* d_out, int out_size, void* d_ws, size_t ws_size,
                              hipStream_t stream) {
  const int* tokens    = (const int*)d_in[0];
  const float* table   = (const float*)d_in[1];
  const float* qkv_w   = (const float*)d_in[2];
  const float* out_w   = (const float*)d_in[3];
  const float* up_w    = (const float*)d_in[4];
  const float* down_w  = (const float*)d_in[5];
  const float* vocab_w = (const float*)d_in[6];
  float* logits = (float*)d_out;

  constexpr int G8_LDS = 131072;
  hipFuncSetAttribute(reinterpret_cast<const void*>(&gemm8_kernel<0>),
                      hipFuncAttributeMaxDynamicSharedMemorySize, G8_LDS);
  hipFuncSetAttribute(reinterpret_cast<const void*>(&gemm8_kernel<2>),
                      hipFuncAttributeMaxDynamicSharedMemorySize, G8_LDS);

  char* p = (char*)d_ws;
  auto alloc = [&](size_t bytes) {
    char* r = p;
    p += (bytes + 255) & ~(size_t)255;
    return r;
  };
  float*  emb    = (float*)alloc(2048ull * 1024 * 4);
  ushort* normed = (ushort*)alloc(2048ull * 1024 * 2);
  float*  qkvbuf = (float*)alloc(2048ull * 3072 * 4);
  ushort* qhb    = (ushort*)alloc(16ull * 2048 * 64 * 2);
  ushort* khb    = (ushort*)alloc(16ull * 2048 * 64 * 2);
  ushort* vtb    = (ushort*)alloc(16ull * 64 * 2048 * 2);
  ushort* attno  = (ushort*)alloc(2048ull * 1024 * 2);
  ushort* gateup = (ushort*)alloc(2048ull * 8192 * 2);
  ushort* hbuf   = (ushort*)alloc(2048ull * 4096 * 2);
  ushort* qkvT   = (ushort*)alloc(4ull * 3072 * 1024 * 2);
  ushort* outT   = (ushort*)alloc(4ull * 1024 * 1024 * 2);
  ushort* upT    = (ushort*)alloc(4ull * 8192 * 1024 * 2);
  ushort* downT  = (ushort*)alloc(4ull * 1024 * 4096 * 2);
  ushort* vocabT = (ushort*)alloc(32000ull * 1024 * 2);

  const dim3 tb(32, 8);
  for (int l = 0; l < 4; ++l) {
    transpose_conv_kernel<<<dim3(3072 / 32, 1024 / 32), tb, 0, stream>>>(
        qkv_w + (size_t)l * 1024 * 3072, qkvT + (size_t)l * 3072 * 1024, 1024, 3072);
    transpose_conv_kernel<<<dim3(1024 / 32, 1024 / 32), tb, 0, stream>>>(
        out_w + (size_t)l * 1024 * 1024, outT + (size_t)l * 1024 * 1024, 1024, 1024);
    transpose_conv_kernel<<<dim3(8192 / 32, 1024 / 32), tb, 0, stream>>>(
        up_w + (size_t)l * 1024 * 8192, upT + (size_t)l * 8192 * 1024, 1024, 8192);
    transpose_conv_kernel<<<dim3(1024 / 32, 4096 / 32), tb, 0, stream>>>(
        down_w + (size_t)l * 4096 * 1024, downT + (size_t)l * 1024 * 4096, 4096, 1024);
  }
  transpose_conv_kernel<<<dim3(32000 / 32, 1024 / 32), tb, 0, stream>>>(
      vocab_w, vocabT, 1024, 32000);

  embed_kernel<<<2048, 256, 0, stream>>>(tokens, table, emb);

  for (int l = 0; l < 4; ++l) {
    rmsnorm_kernel<<<2048, 256, 0, stream>>>(emb, normed);
    gemm8_kernel<0><<<(3072 / 256) * (2048 / 256), 512, G8_LDS, stream>>>(
        normed, qkvT + (size_t)l * 3072 * 1024, nullptr, qkvbuf,
        2048, 3072, 1024, 3072 / 256);
    rope_kernel<<<2048, 256, 0, stream>>>(qkvbuf, qhb, khb);
    vtrans_kernel<<<dim3(32, 16), 256, 0, stream>>>(qkvbuf, vtb);
    attn_mfma_kernel<<<dim3(32, 16), 256, 0, stream>>>(qhb, khb, vtb, attno);
    gemm_bt_kernel<64, 128, 1><<<dim3(1024 / 128, 2048 / 64), 256, 0, stream>>>(
        attno, outT + (size_t)l * 1024 * 1024, emb, emb, 2048, 1024, 1024);
    rmsnorm_kernel<<<2048, 256, 0, stream>>>(emb, normed);
    gemm8_kernel<2><<<(8192 / 256) * (2048 / 256), 512, G8_LDS, stream>>>(
        normed, upT + (size_t)l * 8192 * 1024, nullptr, gateup,
        2048, 8192, 1024, 8192 / 256);
    silu_mul_kernel<<<8192, 256, 0, stream>>>(gateup, hbuf);
    gemm_bt_kernel<64, 128, 1><<<dim3(1024 / 128, 2048 / 64), 256, 0, stream>>>(
        hbuf, downT + (size_t)l * 1024 * 4096, emb, emb, 2048, 1024, 4096);
  }
  rmsnorm_kernel<<<2048, 256, 0, stream>>>(emb, normed);
  gemm8_kernel<0><<<(32000 / 256) * (2048 / 256), 512, G8_LDS, stream>>>(
      normed, vocabT, nullptr, logits, 2048, 32000, 1024, 32000 / 256);
}